// Round 6
// baseline (647.356 us; speedup 1.0000x reference)
//
#include <hip/hip_runtime.h>

typedef __attribute__((ext_vector_type(8))) short bf16x8;   // 8 bf16 = 4 VGPRs
typedef __attribute__((ext_vector_type(4))) float f32x4;    // MFMA C/D

__device__ __forceinline__ float bf2f(unsigned short u){
    unsigned int v = ((unsigned int)u) << 16;
    return __builtin_bit_cast(float, v);
}
__device__ __forceinline__ unsigned short f2bf(float f){
    unsigned int u = __builtin_bit_cast(unsigned int, f);
    u += 0x7FFFu + ((u >> 16) & 1u);   // RTNE
    return (unsigned short)(u >> 16);
}
// pack two floats -> (bf16(a) | bf16(b)<<16), round-half-up: 3 VALU ops
__device__ __forceinline__ unsigned int pack2(float a, float b){
    unsigned int ua = __builtin_bit_cast(unsigned int, a) + 0x8000u;
    unsigned int ub = __builtin_bit_cast(unsigned int, b) + 0x8000u;
    return __builtin_amdgcn_perm(ub, ua, 0x07060302u);
}

// ---- prep: W (K x 256) fp32 -> Wt (256 x K) bf16, LDS-tiled transpose ----
__global__ void prep_wt(const float* __restrict__ W, unsigned short* __restrict__ Wt, int K){
    __shared__ unsigned short L[256 * 72];
    const int t = threadIdx.x;                      // t = j
    const int k0 = blockIdx.x << 6;
    #pragma unroll 4
    for (int kk = 0; kk < 64; kk++)
        L[t * 72 + kk] = f2bf(W[(size_t)(k0 + kk) * 256 + t]);
    __syncthreads();
    const uint4* src = (const uint4*)(L + t * 72);
    uint4* dst = (uint4*)(Wt + (size_t)t * K + k0);
    #pragma unroll
    for (int q = 0; q < 8; q++) dst[q] = src[q];
}

// ---- prep: x (b,m,d) fp32 -> Xt[b][d][m] bf16, LDS transpose ----
__global__ void prep_x(const float* __restrict__ x, unsigned short* __restrict__ Xt){
    __shared__ unsigned short L[64 * 40];
    const int b = blockIdx.x;
    const int t = threadIdx.x;
    #pragma unroll
    for (int it = 0; it < 8; it++){
        int idx = it * 256 + t;
        int m = idx >> 6, d = idx & 63;
        L[d * 40 + m] = f2bf(x[(size_t)b * 2048 + idx]);
    }
    __syncthreads();
    uint4 v = *(const uint4*)(L + (t >> 2) * 40 + (t & 3) * 8);
    *(uint4*)(Xt + (size_t)b * 2048 + t * 8) = v;
}

__global__ void init_out(float* __restrict__ out, const float* __restrict__ fcb){
    int i = blockIdx.x * 256 + threadIdx.x;
    if (i < 1024) out[i] = fcb[0];
}

// ---- fused CIN stage: 512 threads = 8 waves; wave = (j-quarter)x(c-half) ----
// Block: 128 c (2 batch elems). Z double-buffered, ONE barrier per kt.
template<int NN, int LOG2NN, int KTOT, int JX, bool HAS_HOUT>
__global__ __launch_bounds__(512, 4) void cin_stage(
    const unsigned short* __restrict__ Xt,
    const unsigned short* __restrict__ Hin,
    const unsigned short* __restrict__ Wt,
    const float* __restrict__ bias,
    const float* __restrict__ fcW,      // pre-offset for this layer
    unsigned short* __restrict__ Hout,  // [b][d][n] bf16, n in [0,128)
    float* __restrict__ out)
{
    constexpr int KT = KTOT / 32;
    constexpr int ZS = 40;                           // Z row stride (shorts)
    constexpr int XS = 136;                          // Xl2 [m][c pad]
    constexpr int HS = (NN == 32) ? 40 : 136;        // Hl [c][n pad]

    __shared__ unsigned short smem[32000];           // 64000 B -> 2 blocks/CU
    unsigned short* const Zb0 = smem;                // [128][40]
    unsigned short* const Zb1 = smem + 5120;         // [128][40]
    unsigned short* const Xl2 = smem + 10240;        // [32][136]
    unsigned short* const Hl  = smem + 14592;        // [128][HS]
    unsigned short* const Yl  = smem + 14592;        // epilogue overlay [c:128][136]

    const int t    = threadIdx.x;
    const int lane = t & 63;
    const int w    = t >> 6;            // 0..7
    const int jw   = w & 3;             // j-quarter: j in [64*jw, 64*jw+64)
    const int ch   = w >> 2;            // c-half:    c in [64*ch, 64*ch+64)
    const int li   = lane & 15;
    const int lq   = lane >> 4;
    const int bpair = blockIdx.x;

    // ---- one-time staging: x -> Xl2 (transposed), h -> Hl ----
    // 512 threads: 4 threads per c; thread v handles quarter v of each row.
    {
        const int c = t >> 2, v = t & 3;             // c 0..127, v 0..3
        const int be = (bpair << 1) + (c >> 6), d = c & 63;
        // x row: 32 shorts; thread v covers m = v*8 .. v*8+7
        uint4 xa = ((const uint4*)(Xt + ((size_t)be << 11) + (d << 5)))[v];
        #pragma unroll
        for (int q = 0; q < 8; q++)
            Xl2[(v * 8 + q) * XS + c] = ((const unsigned short*)&xa)[q];
        if (NN == 128){
            // h row: 128 shorts; thread v covers n = v*32 .. v*32+31
            const uint4* hsrc = (const uint4*)(Hin + (size_t)((be << 6) + d) * 128 + v * 32);
            #pragma unroll
            for (int q = 0; q < 4; q++){
                uint4 hv = hsrc[q];
                *(uint4*)(Hl + c * HS + v * 32 + q * 8) = hv;
            }
        } else {
            // NN==32: h row = Xt row (32 shorts); thread v covers n = v*8 .. v*8+7
            uint4 hv = ((const uint4*)(Hin + ((size_t)be << 11) + (d << 5)))[v];
            *(uint4*)(Hl + c * HS + v * 8) = hv;
        }
    }

    // Z-build: thread (zc, zq) fills Zb[zc][zq*8 .. +8)
    const int zc = t & 127;
    const int zq = t >> 7;              // 0..3
    auto build = [&](unsigned short* zbuf, int kt){
        const int kg = (kt << 5) + (zq << 3);
        const int m  = kg >> LOG2NN;
        const int n0 = kg & (NN - 1);
        float xf = bf2f(Xl2[m * XS + zc]);
        uint2 h = *(const uint2*)(Hl + zc * HS + n0);
        const unsigned short* hu = (const unsigned short*)&h;
        uint2 z;
        unsigned int* zp = (unsigned int*)&z;
        #pragma unroll
        for (int q = 0; q < 2; q++)
            zp[q] = pack2(xf * bf2f(hu[2 * q]), xf * bf2f(hu[2 * q + 1]));
        uint2 h2 = *(const uint2*)(Hl + zc * HS + n0 + 4);
        const unsigned short* hu2 = (const unsigned short*)&h2;
        uint2 z2;
        unsigned int* zp2 = (unsigned int*)&z2;
        #pragma unroll
        for (int q = 0; q < 2; q++)
            zp2[q] = pack2(xf * bf2f(hu2[2 * q]), xf * bf2f(hu2[2 * q + 1]));
        uint4 zv;
        zv.x = z.x; zv.y = z.y; zv.z = z2.x; zv.w = z2.y;
        *(uint4*)(zbuf + zc * ZS + (zq << 3)) = zv;
    };

    // A-fragments: lane reads Wt[j = jw*64 + jj*16 + li][kt*32 + lq*8 .. +8)
    const unsigned short* wbase = Wt + (size_t)((jw << 6) + li) * KTOT + (lq << 3);
    auto loadA = [&](int kt, bf16x8* A){
        const unsigned short* wk = wbase + (kt << 5);
        #pragma unroll
        for (int jj = 0; jj < 4; jj++)
            A[jj] = *(const bf16x8*)(wk + (size_t)jj * 16 * KTOT);
    };

    f32x4 acc[4][4];
    #pragma unroll
    for (int jj = 0; jj < 4; jj++)
        #pragma unroll
        for (int cc = 0; cc < 4; cc++)
            acc[jj][cc] = (f32x4){0.f, 0.f, 0.f, 0.f};

    auto mfma_step = [&](const unsigned short* Zr, const bf16x8* A){
        #pragma unroll
        for (int cc = 0; cc < 4; cc++){
            const int ct = (ch << 2) + cc;
            bf16x8 B = *(const bf16x8*)(Zr + ((ct << 4) + li) * ZS + (lq << 3));
            #pragma unroll
            for (int jj = 0; jj < 4; jj++)
                acc[jj][cc] = __builtin_amdgcn_mfma_f32_16x16x32_bf16(A[jj], B, acc[jj][cc], 0, 0, 0);
        }
    };

    bf16x8 A0[4], A1[4];
    loadA(0, A0);
    __syncthreads();            // staging visible
    build(Zb0, 0);
    __syncthreads();

    // 2x-unrolled K loop: ONE barrier per kt
    for (int kt = 0; kt < KT; kt += 2){
        loadA(kt + 1, A1);
        mfma_step(Zb0, A0);
        build(Zb1, kt + 1);
        __syncthreads();
        if (kt + 2 < KT) loadA(kt + 2, A0);
        mfma_step(Zb1, A1);
        if (kt + 2 < KT) build(Zb0, kt + 2);
        __syncthreads();
    }

    // ---- epilogue: bias+relu, fc partial, h-half -> Yl[c][n] ----
    float pfc = 0.f;
    #pragma unroll
    for (int jj = 0; jj < 4; jj++){
        const int jb = (jw << 6) + (jj << 4) + (lq << 2);
        float bv[4], fv[4];
        #pragma unroll
        for (int r = 0; r < 4; r++){
            int j = jb + r;
            bv[r] = bias[j];
            fv[r] = (j < JX) ? fcW[j] : 0.f;
        }
        #pragma unroll
        for (int cc = 0; cc < 4; cc++){
            f32x4 f = acc[jj][cc];
            const int c = (((ch << 2) + cc) << 4) + li;
            float y0 = f[0] + bv[0]; y0 = y0 > 0.f ? y0 : 0.f;
            float y1 = f[1] + bv[1]; y1 = y1 > 0.f ? y1 : 0.f;
            float y2 = f[2] + bv[2]; y2 = y2 > 0.f ? y2 : 0.f;
            float y3 = f[3] + bv[3]; y3 = y3 > 0.f ? y3 : 0.f;
            pfc += fv[0] * y0 + fv[1] * y1 + fv[2] * y2 + fv[3] * y3;
            if (HAS_HOUT && jw >= 2){                // j >= 128: h-half
                uint2 pk;
                pk.x = pack2(y0, y1);
                pk.y = pack2(y2, y3);
                *(uint2*)(Yl + c * 136 + (jb - 128)) = pk;
            }
        }
    }
    #pragma unroll
    for (int off = 32; off; off >>= 1) pfc += __shfl_xor(pfc, off, 64);
    if (lane == 0) atomicAdd(out + (bpair << 1) + ch, pfc);

    if (HAS_HOUT){
        __syncthreads();
        // Hout[(bpair*128 + c)*128 + n] = Yl[c][n]; thread v covers n = v*32..+31
        const int c2 = t >> 2, v2 = t & 3;
        unsigned short* gdst = Hout + (size_t)((bpair << 7) + c2) * 128 + v2 * 32;
        #pragma unroll
        for (int q = 0; q < 4; q++){
            uint4 tv = *(const uint4*)(Yl + c2 * 136 + v2 * 32 + q * 8);
            *(uint4*)(gdst + q * 8) = tv;
        }
    }
}

extern "C" void kernel_launch(void* const* d_in, const int* in_sizes, int n_in,
                              void* d_out, int out_size, void* d_ws, size_t ws_size,
                              hipStream_t stream){
    const float* x   = (const float*)d_in[0];
    const float* W0  = (const float*)d_in[1];
    const float* b0  = (const float*)d_in[2];
    const float* W1  = (const float*)d_in[3];
    const float* b1  = (const float*)d_in[4];
    const float* W2  = (const float*)d_in[5];
    const float* b2  = (const float*)d_in[6];
    const float* fcW = (const float*)d_in[7];
    const float* fcb = (const float*)d_in[8];
    float* out = (float*)d_out;

    char* ws = (char*)d_ws;
    unsigned short* Xt  = (unsigned short*)(ws);             // 4 MB
    unsigned short* Wt0 = (unsigned short*)(ws + 4194304);   // 512 KB
    unsigned short* Wt1 = (unsigned short*)(ws + 4718592);   // 2 MB
    unsigned short* Wt2 = (unsigned short*)(ws + 6815744);   // 2 MB
    unsigned short* H0  = (unsigned short*)(ws + 8912896);   // 16 MB
    unsigned short* H1  = (unsigned short*)(ws + 25690112);  // 16 MB (end 42467328)

    prep_wt<<<  16, 256, 0, stream>>>(W0, Wt0, 1024);
    prep_wt<<<  64, 256, 0, stream>>>(W1, Wt1, 4096);
    prep_wt<<<  64, 256, 0, stream>>>(W2, Wt2, 4096);
    prep_x <<<1024, 256, 0, stream>>>(x, Xt);
    init_out<<<4, 256, 0, stream>>>(out, fcb);

    cin_stage< 32, 5, 1024, 128, true ><<<512, 512, 0, stream>>>(Xt, Xt, Wt0, b0, fcW,       H0, out);
    cin_stage<128, 7, 4096, 128, true ><<<512, 512, 0, stream>>>(Xt, H0, Wt1, b1, fcW + 128, H1, out);
    cin_stage<128, 7, 4096, 256, false><<<512, 512, 0, stream>>>(Xt, H1, Wt2, b2, fcW + 256, nullptr, out);
}